// Round 3
// baseline (214.460 us; speedup 1.0000x reference)
//
#include <hip/hip_runtime.h>
#include <math.h>

// ---------------------------------------------------------------------------
// QFCModel fused: avgpool(6) -> linear(16->4) -> 4-qubit circuit -> linear -> BN
//
// R11: remove LDS staging of x entirely (discriminating experiment).
// R8/R9/R10 all pinned at ~60us with every pipe idle (VALU 24%, HBM 9.5%,
// conflicts 0) across three different schedules; the common mechanism is
// global_load_lds DMA on cold-HBM data. This version loads each thread's
// 6x6 pool window directly with 18 x float2 flat loads (8B-aligned, fully
// unrolled => 18-deep MLP/thread, ~20 waves/CU of TLP), LDS holds only the
// tiny V/W2 tables. One barrier (before matvec). Math identical to R10.
// Predicted: fused 60 -> 22-32us if DMA was the limit; unchanged if the
// kernel is harness-BW-starved.
// ---------------------------------------------------------------------------

#define BTOT 32768
#define SPB  16           // samples per block
#define NBLK (BTOT / SPB) // 2048 fused blocks

__device__ float g_partials[NBLK * 8];   // static scratch: d_ws untouched

// ---- fused: direct-load pool->encode->circuit->classify + BN partials -----
__global__ __launch_bounds__(256) void fused_kernel(
    const float* __restrict__ x,
    const float* __restrict__ enc_w, const float* __restrict__ enc_b,
    const float* __restrict__ qparams, const float* __restrict__ cls_w,
    const float* __restrict__ cls_b,
    float* __restrict__ preBN)
{
    __shared__ float sVr[16 * 17];       // stride 17: 17k mod 32 injective
    __shared__ float sVi[16 * 17];
    __shared__ float sW2[4 * 17];
    __shared__ float red[4][8];

    const int tid = threadIdx.x;
    const int s0  = blockIdx.x * SPB;
    const int s = tid >> 4, cell = tid & 15;
    const int cr = cell >> 2, cc = cell & 3;

    // ---- issue all 18 pool-window loads first (maximize MLP) --------------
    // addr = x + (s0+s)*784 + (cr*6+r)*28 + cc*6 + o*2 ; all 8B-aligned.
    const float2* pb =
        (const float2*)(x + (size_t)(s0 + s) * 784 + (cr * 6) * 28 + cc * 6);
    float2 v[6][3];
    #pragma unroll
    for (int r = 0; r < 6; ++r) {
        #pragma unroll
        for (int o = 0; o < 3; ++o)
            v[r][o] = pb[r * 14 + o];    // 28 floats = 14 float2 per row
    }

    // ---- in-block prep (wave 0), overlaps the loads above -----------------
    if (tid < 64) {
        {   // W2[j][i] = sum_w cls_w[j][w] * sign_w(i)
            int j = tid >> 4, i = tid & 15;
            float acc = 0.f;
            #pragma unroll
            for (int w = 0; w < 4; ++w)
                acc += cls_w[j * 4 + w] * ((i & (8 >> w)) ? -1.f : 1.f);
            sW2[j * 17 + i] = acc;
        }
        if (tid < 16) {
            // simulate variational layers on basis state e_t -> column t of U
            const int t = tid;
            float pr[16], pi[16];
            #pragma unroll
            for (int i = 0; i < 16; ++i) { pr[i] = (i == t) ? 1.f : 0.f; pi[i] = 0.f; }
            #pragma unroll
            for (int layer = 0; layer < 3; ++layer) {
                #pragma unroll
                for (int w = 0; w < 4; ++w) {
                    const float* qp = qparams + (layer * 4 + w) * 3;
                    float phi = qp[0], th = qp[1], om = qp[2];
                    float c, sn, ca, sa, cd, sd;
                    __sincosf(0.5f * th, &sn, &c);
                    __sincosf(0.5f * (phi + om), &sa, &ca);
                    __sincosf(0.5f * (phi - om), &sd, &cd);
                    float u00r =  c * ca, u00i = -c * sa;
                    float u01r = -sn * cd, u01i = -sn * sd;
                    float u10r =  sn * cd, u10i = -sn * sd;
                    float u11r =  c * ca, u11i =  c * sa;
                    const int m = 8 >> w;   // wire 0 = MSB
                    #pragma unroll
                    for (int idx = 0; idx < 16; ++idx) {
                        if (idx & m) continue;
                        const int i1 = idx | m;
                        float ar = pr[idx], ai = pi[idx], br = pr[i1], bi = pi[i1];
                        pr[idx] = u00r*ar - u00i*ai + u01r*br - u01i*bi;
                        pi[idx] = u00r*ai + u00i*ar + u01r*bi + u01i*br;
                        pr[i1]  = u10r*ar - u10i*ai + u11r*br - u11i*bi;
                        pi[i1]  = u10r*ai + u10i*ar + u11r*bi + u11i*br;
                    }
                }
                #pragma unroll
                for (int w = 0; w < 3; ++w) {  // CNOT ladder (register renames)
                    const int mc = 8 >> w, mt = 8 >> (w + 1);
                    #pragma unroll
                    for (int idx = 0; idx < 16; ++idx) {
                        if ((idx & mc) && !(idx & mt)) {
                            const int i1 = idx | mt;
                            float tr = pr[idx], ti = pi[idx];
                            pr[idx] = pr[i1]; pi[idx] = pi[i1];
                            pr[i1] = tr;      pi[i1] = ti;
                        }
                    }
                }
            }
            // fold (-i)^popcount(column t)
            const int p = __popc(t) & 3;
            #pragma unroll
            for (int i = 0; i < 16; ++i) {
                float re = pr[i], im = pi[i], vr, vi;
                if (p == 0)      { vr = re;  vi = im;  }
                else if (p == 1) { vr = im;  vi = -re; }
                else if (p == 2) { vr = -re; vi = -im; }
                else             { vr = -im; vi = re;  }
                sVr[i * 17 + t] = vr;
                sVi[i * 17 + t] = vi;
            }
        }
    }

    // ---- pool sum ---------------------------------------------------------
    float sum = 0.f;
    #pragma unroll
    for (int r = 0; r < 6; ++r) {
        float2 a = v[r][0], b = v[r][1], c2 = v[r][2];
        sum += (a.x + a.y) + (b.x + b.y) + (c2.x + c2.y);
    }
    const float pv = sum * (1.f / 36.f);

    // ---- encode: z_j = sum_cells enc_w[j][cell]*pv, 16-lane xor-reduce ----
    float z[4];
    #pragma unroll
    for (int j = 0; j < 4; ++j) z[j] = enc_w[j * 16 + cell] * pv;
    #pragma unroll
    for (int m = 1; m <= 8; m <<= 1) {
        #pragma unroll
        for (int j = 0; j < 4; ++j) z[j] += __shfl_xor(z[j], m, 64);
    }
    #pragma unroll
    for (int j = 0; j < 4; ++j) z[j] += enc_b[j];

    // ---- product state r_k ------------------------------------------------
    float cz[4], sz[4];
    #pragma unroll
    for (int j = 0; j < 4; ++j) __sincosf(0.5f * z[j], &sz[j], &cz[j]);
    float a01[4] = {cz[0]*cz[1], cz[0]*sz[1], sz[0]*cz[1], sz[0]*sz[1]};
    float a23[4] = {cz[2]*cz[3], cz[2]*sz[3], sz[2]*cz[3], sz[2]*sz[3]};
    float rv[16];
    #pragma unroll
    for (int k = 0; k < 16; ++k) rv[k] = a01[k >> 2] * a23[k & 3];

    __syncthreads();   // sVr/sVi/sW2 ready (wave 0 prep)

    // ---- matvec row i = cell; prob; partial classifier --------------------
    float ar = 0.f, ai = 0.f;
    #pragma unroll
    for (int k = 0; k < 16; ++k) {
        ar += sVr[cell * 17 + k] * rv[k];
        ai += sVi[cell * 17 + k] * rv[k];
    }
    const float prob = ar * ar + ai * ai;
    float out[4];
    #pragma unroll
    for (int j = 0; j < 4; ++j) out[j] = sW2[j * 17 + cell] * prob;
    #pragma unroll
    for (int m = 1; m <= 8; m <<= 1) {
        #pragma unroll
        for (int j = 0; j < 4; ++j) out[j] += __shfl_xor(out[j], m, 64);
    }
    #pragma unroll
    for (int j = 0; j < 4; ++j) out[j] += cls_b[j];

    if (cell == 0)
        ((float4*)preBN)[s0 + s] = make_float4(out[0], out[1], out[2], out[3]);

    // ---- BN partials: one contribution per sample (cell==0 lanes) ---------
    const float w = (cell == 0) ? 1.f : 0.f;
    float v8[8] = {out[0]*w, out[1]*w, out[2]*w, out[3]*w,
                   out[0]*out[0]*w, out[1]*out[1]*w, out[2]*out[2]*w, out[3]*out[3]*w};
    #pragma unroll
    for (int m = 0; m < 8; ++m) {
        v8[m] += __shfl_down(v8[m], 32, 64);
        v8[m] += __shfl_down(v8[m], 16, 64);
    }
    const int wave = tid >> 6, lane = tid & 63;
    if (lane == 0) {
        #pragma unroll
        for (int m = 0; m < 8; ++m) red[wave][m] = v8[m];
    }
    __syncthreads();
    if (tid < 8)
        g_partials[blockIdx.x * 8 + tid] =
            red[0][tid] + red[1][tid] + red[2][tid] + red[3][tid];
}

// ---- kernel 2: reduce partials (redundantly per block) + batch-norm -------
__global__ __launch_bounds__(256) void bn_kernel(
    const float* __restrict__ gamma, const float* __restrict__ beta,
    float* __restrict__ out)
{
    const int tid = threadIdx.x;
    float acc[8] = {0, 0, 0, 0, 0, 0, 0, 0};
    const float4* p4 = (const float4*)g_partials;
    #pragma unroll
    for (int it = 0; it < NBLK / 256; ++it) {
        int b = it * 256 + tid;
        float4 a = p4[b * 2], c = p4[b * 2 + 1];
        acc[0] += a.x; acc[1] += a.y; acc[2] += a.z; acc[3] += a.w;
        acc[4] += c.x; acc[5] += c.y; acc[6] += c.z; acc[7] += c.w;
    }
    #pragma unroll
    for (int off = 32; off >= 1; off >>= 1) {
        #pragma unroll
        for (int m = 0; m < 8; ++m) acc[m] += __shfl_xor(acc[m], off, 64);
    }
    __shared__ float red[4][8];
    const int wave = tid >> 6, lane = tid & 63;
    if (lane == 0) {
        #pragma unroll
        for (int m = 0; m < 8; ++m) red[wave][m] = acc[m];
    }
    __syncthreads();
    float sums[8];
    #pragma unroll
    for (int m = 0; m < 8; ++m)
        sums[m] = red[0][m] + red[1][m] + red[2][m] + red[3][m];

    const int s = blockIdx.x * 256 + tid;
    const float invB = 1.f / (float)BTOT;
    float4 v = ((const float4*)out)[s];
    float o[4] = {v.x, v.y, v.z, v.w};
    #pragma unroll
    for (int j = 0; j < 4; ++j) {
        float mu   = sums[j] * invB;
        float var  = sums[4 + j] * invB - mu * mu;
        float rstd = rsqrtf(var + 1e-5f);
        o[j] = (o[j] - mu) * rstd * gamma[j] + beta[j];
    }
    ((float4*)out)[s] = make_float4(o[0], o[1], o[2], o[3]);
}

extern "C" void kernel_launch(void* const* d_in, const int* in_sizes, int n_in,
                              void* d_out, int out_size, void* d_ws, size_t ws_size,
                              hipStream_t stream)
{
    const float* x        = (const float*)d_in[0];
    const float* enc_w    = (const float*)d_in[1];
    const float* enc_b    = (const float*)d_in[2];
    const float* qparams  = (const float*)d_in[3];
    const float* cls_w    = (const float*)d_in[4];
    const float* cls_b    = (const float*)d_in[5];
    const float* bn_gamma = (const float*)d_in[6];
    const float* bn_beta  = (const float*)d_in[7];

    float* outp = (float*)d_out;     // pre-BN scratch == final out
    (void)d_ws; (void)ws_size;       // ws poison is unconditional (R9 result)

    fused_kernel<<<NBLK, 256, 0, stream>>>(x, enc_w, enc_b, qparams, cls_w,
                                           cls_b, outp);
    bn_kernel<<<128, 256, 0, stream>>>(bn_gamma, bn_beta, outp);
}

// Round 4
// 176.515 us; speedup vs baseline: 1.2150x; 1.2150x over previous
//
#include <hip/hip_runtime.h>
#include <math.h>

// ---------------------------------------------------------------------------
// QFCModel fused: avgpool(6) -> linear(16->4) -> 4-qubit circuit -> linear -> BN
//
// R12: coalesced REGISTER staging instead of global_load_lds DMA.
// Evidence: R8/R9/R10 (DMA, three different schedules) all pinned at 60us
// with ~2KB effective in-flight per CU (Little's law from 4.8 GB/s/CU at
// ~900cy latency) -- consistent with the LDS-DMA path serializing per
// instruction on cold-HBM sources. R11 (scattered per-thread loads) was
// worse (131us): 8-B lanes spread over ~48 lines/instr. R12 keeps the DMA
// version's wave-linear contiguous address pattern but issues it as 9x
// global_load_dwordx4 per thread into registers (144KB in flight per CU),
// then ds_write_b128 to the same dense LDS layout. Compute path identical
// to R8 (passed, absmax 0.0156).
// ---------------------------------------------------------------------------

#define BTOT 32768
#define SPB  16           // samples per block
#define NBLK (BTOT / SPB) // 2048 fused blocks
#define SSTR 576          // LDS floats per sample: 24 rows x 24 cols, dense

__device__ float g_partials[NBLK * 8];   // static scratch: d_ws untouched

// ---- fused: reg-stage->pool->encode->circuit->classify + BN partials ------
__global__ __launch_bounds__(256) void fused_kernel(
    const float* __restrict__ x,
    const float* __restrict__ enc_w, const float* __restrict__ enc_b,
    const float* __restrict__ qparams, const float* __restrict__ cls_w,
    const float* __restrict__ cls_b,
    float* __restrict__ preBN)
{
    __shared__ __align__(16) float sx[SPB * SSTR];  // 36864 B, dense
    __shared__ float sVr[16 * 17];       // stride 17: 17k mod 32 injective
    __shared__ float sVi[16 * 17];
    __shared__ float sW2[4 * 17];
    __shared__ float red[4][8];

    const int tid = threadIdx.x;
    const int s0  = blockIdx.x * SPB;
    const float4* xb = (const float4*)x;

    // ---- stage 24x24 region of 16 samples: 2304 f4 = 9 rounds of 256 -----
    // Wave-linear, mostly-contiguous (1KB/wave/instr): issue ALL 9 loads
    // into registers first (9KB outstanding per wave), ds_write later.
    float4 st[9];
    #pragma unroll
    for (int it = 0; it < 9; ++it) {
        const int gid  = it * 256 + tid;
        const int c    = gid / 144;            // sample within block
        const int o    = gid - c * 144;        // f4 within 24x24 region
        const int row  = o / 6;
        const int col4 = o - row * 6;
        st[it] = xb[(size_t)(s0 + c) * 196 + row * 7 + col4];
    }

    // ---- in-block prep (wave 0) overlaps the x-load miss latency ----------
    if (tid < 64) {
        {   // W2[j][i] = sum_w cls_w[j][w] * sign_w(i)
            int j = tid >> 4, i = tid & 15;
            float acc = 0.f;
            #pragma unroll
            for (int w = 0; w < 4; ++w)
                acc += cls_w[j * 4 + w] * ((i & (8 >> w)) ? -1.f : 1.f);
            sW2[j * 17 + i] = acc;
        }
        if (tid < 16) {
            // simulate variational layers on basis state e_t -> column t of U
            const int t = tid;
            float pr[16], pi[16];
            #pragma unroll
            for (int i = 0; i < 16; ++i) { pr[i] = (i == t) ? 1.f : 0.f; pi[i] = 0.f; }
            #pragma unroll
            for (int layer = 0; layer < 3; ++layer) {
                #pragma unroll
                for (int w = 0; w < 4; ++w) {
                    const float* qp = qparams + (layer * 4 + w) * 3;
                    float phi = qp[0], th = qp[1], om = qp[2];
                    float c, sn, ca, sa, cd, sd;
                    __sincosf(0.5f * th, &sn, &c);
                    __sincosf(0.5f * (phi + om), &sa, &ca);
                    __sincosf(0.5f * (phi - om), &sd, &cd);
                    float u00r =  c * ca, u00i = -c * sa;
                    float u01r = -sn * cd, u01i = -sn * sd;
                    float u10r =  sn * cd, u10i = -sn * sd;
                    float u11r =  c * ca, u11i =  c * sa;
                    const int m = 8 >> w;   // wire 0 = MSB
                    #pragma unroll
                    for (int idx = 0; idx < 16; ++idx) {
                        if (idx & m) continue;
                        const int i1 = idx | m;
                        float ar = pr[idx], ai = pi[idx], br = pr[i1], bi = pi[i1];
                        pr[idx] = u00r*ar - u00i*ai + u01r*br - u01i*bi;
                        pi[idx] = u00r*ai + u00i*ar + u01r*bi + u01i*br;
                        pr[i1]  = u10r*ar - u10i*ai + u11r*br - u11i*bi;
                        pi[i1]  = u10r*ai + u10i*ar + u11r*bi + u11i*br;
                    }
                }
                #pragma unroll
                for (int w = 0; w < 3; ++w) {  // CNOT ladder (register renames)
                    const int mc = 8 >> w, mt = 8 >> (w + 1);
                    #pragma unroll
                    for (int idx = 0; idx < 16; ++idx) {
                        if ((idx & mc) && !(idx & mt)) {
                            const int i1 = idx | mt;
                            float tr = pr[idx], ti = pi[idx];
                            pr[idx] = pr[i1]; pi[idx] = pi[i1];
                            pr[i1] = tr;      pi[i1] = ti;
                        }
                    }
                }
            }
            // fold (-i)^popcount(column t)
            const int p = __popc(t) & 3;
            #pragma unroll
            for (int i = 0; i < 16; ++i) {
                float re = pr[i], im = pi[i], vr, vi;
                if (p == 0)      { vr = re;  vi = im;  }
                else if (p == 1) { vr = im;  vi = -re; }
                else if (p == 2) { vr = -re; vi = -im; }
                else             { vr = -im; vi = re;  }
                sVr[i * 17 + t] = vr;
                sVi[i * 17 + t] = vi;
            }
        }
    }

    // ---- write staged registers to dense LDS (conflict-free b128) ---------
    #pragma unroll
    for (int it = 0; it < 9; ++it)
        ((float4*)sx)[it * 256 + tid] = st[it];

    __syncthreads();   // staging + prep visible

    // ---- pool: thread (s, cell); row order rotated by s mod 6 -------------
    const int s = tid >> 4, cell = tid & 15;
    const int cr = cell >> 2, cc = cell & 3;
    int srot = s;                                   // srot = s mod 6
    srot -= (srot >= 12) ? 12 : ((srot >= 6) ? 6 : 0);
    const float* sb = &sx[s * SSTR + cr * 6 * 24 + cc * 6];
    float sum = 0.f;
    #pragma unroll
    for (int rr = 0; rr < 6; ++rr) {
        int r = rr + srot; r -= (r >= 6) ? 6 : 0;   // (rr + s) mod 6
        const float2* rp = (const float2*)(sb + r * 24);
        float2 a = rp[0], b = rp[1], c2 = rp[2];
        sum += (a.x + a.y) + (b.x + b.y) + (c2.x + c2.y);
    }
    const float pv = sum * (1.f / 36.f);

    // ---- encode: z_j = sum_cells enc_w[j][cell]*pv, 16-lane xor-reduce ----
    float z[4];
    #pragma unroll
    for (int j = 0; j < 4; ++j) z[j] = enc_w[j * 16 + cell] * pv;
    #pragma unroll
    for (int m = 1; m <= 8; m <<= 1) {
        #pragma unroll
        for (int j = 0; j < 4; ++j) z[j] += __shfl_xor(z[j], m, 64);
    }
    #pragma unroll
    for (int j = 0; j < 4; ++j) z[j] += enc_b[j];

    // ---- product state r_k ------------------------------------------------
    float cz[4], sz[4];
    #pragma unroll
    for (int j = 0; j < 4; ++j) __sincosf(0.5f * z[j], &sz[j], &cz[j]);
    float a01[4] = {cz[0]*cz[1], cz[0]*sz[1], sz[0]*cz[1], sz[0]*sz[1]};
    float a23[4] = {cz[2]*cz[3], cz[2]*sz[3], sz[2]*cz[3], sz[2]*sz[3]};
    float rv[16];
    #pragma unroll
    for (int k = 0; k < 16; ++k) rv[k] = a01[k >> 2] * a23[k & 3];

    // ---- matvec row i = cell; prob; partial classifier --------------------
    float ar = 0.f, ai = 0.f;
    #pragma unroll
    for (int k = 0; k < 16; ++k) {
        ar += sVr[cell * 17 + k] * rv[k];
        ai += sVi[cell * 17 + k] * rv[k];
    }
    const float prob = ar * ar + ai * ai;
    float out[4];
    #pragma unroll
    for (int j = 0; j < 4; ++j) out[j] = sW2[j * 17 + cell] * prob;
    #pragma unroll
    for (int m = 1; m <= 8; m <<= 1) {
        #pragma unroll
        for (int j = 0; j < 4; ++j) out[j] += __shfl_xor(out[j], m, 64);
    }
    #pragma unroll
    for (int j = 0; j < 4; ++j) out[j] += cls_b[j];

    if (cell == 0)
        ((float4*)preBN)[s0 + s] = make_float4(out[0], out[1], out[2], out[3]);

    // ---- BN partials: one contribution per sample (cell==0 lanes) ---------
    const float w = (cell == 0) ? 1.f : 0.f;
    float v8[8] = {out[0]*w, out[1]*w, out[2]*w, out[3]*w,
                   out[0]*out[0]*w, out[1]*out[1]*w, out[2]*out[2]*w, out[3]*out[3]*w};
    #pragma unroll
    for (int m = 0; m < 8; ++m) {
        v8[m] += __shfl_down(v8[m], 32, 64);
        v8[m] += __shfl_down(v8[m], 16, 64);
    }
    const int wave = tid >> 6, lane = tid & 63;
    if (lane == 0) {
        #pragma unroll
        for (int m = 0; m < 8; ++m) red[wave][m] = v8[m];
    }
    __syncthreads();
    if (tid < 8)
        g_partials[blockIdx.x * 8 + tid] =
            red[0][tid] + red[1][tid] + red[2][tid] + red[3][tid];
}

// ---- kernel 2: reduce partials (redundantly per block) + batch-norm -------
__global__ __launch_bounds__(256) void bn_kernel(
    const float* __restrict__ gamma, const float* __restrict__ beta,
    float* __restrict__ out)
{
    const int tid = threadIdx.x;
    float acc[8] = {0, 0, 0, 0, 0, 0, 0, 0};
    const float4* p4 = (const float4*)g_partials;
    #pragma unroll
    for (int it = 0; it < NBLK / 256; ++it) {
        int b = it * 256 + tid;
        float4 a = p4[b * 2], c = p4[b * 2 + 1];
        acc[0] += a.x; acc[1] += a.y; acc[2] += a.z; acc[3] += a.w;
        acc[4] += c.x; acc[5] += c.y; acc[6] += c.z; acc[7] += c.w;
    }
    #pragma unroll
    for (int off = 32; off >= 1; off >>= 1) {
        #pragma unroll
        for (int m = 0; m < 8; ++m) acc[m] += __shfl_xor(acc[m], off, 64);
    }
    __shared__ float red[4][8];
    const int wave = tid >> 6, lane = tid & 63;
    if (lane == 0) {
        #pragma unroll
        for (int m = 0; m < 8; ++m) red[wave][m] = acc[m];
    }
    __syncthreads();
    float sums[8];
    #pragma unroll
    for (int m = 0; m < 8; ++m)
        sums[m] = red[0][m] + red[1][m] + red[2][m] + red[3][m];

    const int s = blockIdx.x * 256 + tid;
    const float invB = 1.f / (float)BTOT;
    float4 v = ((const float4*)out)[s];
    float o[4] = {v.x, v.y, v.z, v.w};
    #pragma unroll
    for (int j = 0; j < 4; ++j) {
        float mu   = sums[j] * invB;
        float var  = sums[4 + j] * invB - mu * mu;
        float rstd = rsqrtf(var + 1e-5f);
        o[j] = (o[j] - mu) * rstd * gamma[j] + beta[j];
    }
    ((float4*)out)[s] = make_float4(o[0], o[1], o[2], o[3]);
}

extern "C" void kernel_launch(void* const* d_in, const int* in_sizes, int n_in,
                              void* d_out, int out_size, void* d_ws, size_t ws_size,
                              hipStream_t stream)
{
    const float* x        = (const float*)d_in[0];
    const float* enc_w    = (const float*)d_in[1];
    const float* enc_b    = (const float*)d_in[2];
    const float* qparams  = (const float*)d_in[3];
    const float* cls_w    = (const float*)d_in[4];
    const float* cls_b    = (const float*)d_in[5];
    const float* bn_gamma = (const float*)d_in[6];
    const float* bn_beta  = (const float*)d_in[7];

    float* outp = (float*)d_out;     // pre-BN scratch == final out
    (void)d_ws; (void)ws_size;       // ws poison is unconditional (R9 result)

    fused_kernel<<<NBLK, 256, 0, stream>>>(x, enc_w, enc_b, qparams, cls_w,
                                           cls_b, outp);
    bn_kernel<<<128, 256, 0, stream>>>(bn_gamma, bn_beta, outp);
}